// Round 7
// baseline (28.452 us; speedup 1.0000x reference)
//
#include <hip/hip_runtime.h>

// AtomDistances: out[b,i,j] = mask[b,i]&&mask[b,j]&&(i!=j)
//                  ? 1/(safe_norm(pos[b,nbr[b,i,j]] - pos[b,i]) + 1e-8) : 0
// B=4, A=2048.
//
// R7 = R6 + issue/latency cuts:
//  - 8 j's per lane (2x int4 / 2x f4 per chunk, 4 chunks/row): per-chunk fixed
//    overhead amortized 2x, one mask-word read covers 8 elements.
//  - neighbor prefetch issued BEFORE __syncthreads (hidden under staging),
//    gated by a wave-uniform global mask probe.
//  - fminf(rsq(d2), 1e8) replaces the d2==0 cmp+select (rsq(0)=inf -> 1e8,
//    matches ref 1/(0+1e-8) exactly; randn positions can't produce d2 in the
//    (0, 1e-14) band where min vs ref would differ beyond threshold).
// Known-dead ends: LDS-conflict cuts (R6 flat), global-atomic tickets (R5,
// 10x regression), prepass kernel (R4, serial node).

typedef float f4 __attribute__((ext_vector_type(4)));
typedef float f2 __attribute__((ext_vector_type(2)));

constexpr int A_DIM = 2048;
constexpr int WPB   = 8;          // rows (waves) per block
constexpr int NTHR  = WPB * 64;   // 512

__global__ __launch_bounds__(NTHR, 8) void atom_distances_kernel(
    const float* __restrict__ pos,    // [B, A, 3]
    const int*   __restrict__ nbr,    // [B, A, A]
    const int*   __restrict__ mask,   // [B, A]
    float*       __restrict__ out) {  // [B, A, A]
  __shared__ float    sx[A_DIM];             // 8 KB
  __shared__ f2       syz[A_DIM];            // 16 KB
  __shared__ unsigned smaskbits[A_DIM / 32]; // 256 B

  const int blocks_per_b = A_DIM / WPB;      // 256
  const int b  = blockIdx.x / blocks_per_b;
  const int i0 = (blockIdx.x % blocks_per_b) * WPB;

  const float* posb  = pos  + (size_t)b * A_DIM * 3;
  const int*   maskb = mask + (size_t)b * A_DIM;

  const int w    = threadIdx.x >> 6;
  const int lane = threadIdx.x & 63;
  const int i    = i0 + w;

  const int  mi   = maskb[i];                // wave-uniform broadcast load
  const int* nrow = nbr + ((size_t)b * A_DIM + i) * A_DIM;

  // chunk c, half h: int4 at (c*64+lane)*8 + h*4
#define LDN(c, h) (*reinterpret_cast<const int4*>(nrow + ((c) * 64 + lane) * 8 + (h) * 4))

  // prefetch chunks 0,1 BEFORE the barrier: latency hides under LDS staging
  int4 nA0, nB0, nA1, nB1;
  if (mi) { nA0 = LDN(0, 0); nB0 = LDN(0, 1); nA1 = LDN(1, 0); nB1 = LDN(1, 1); }

  for (int t = threadIdx.x; t < A_DIM; t += NTHR) {
    sx[t] = posb[3 * t + 0];
    f2 yz; yz.x = posb[3 * t + 1]; yz.y = posb[3 * t + 2];
    syz[t] = yz;
  }
  for (int r = 0; r < A_DIM / NTHR; ++r) {   // 4 rounds
    const int t = r * NTHR + threadIdx.x;
    const unsigned long long bal = __ballot(maskb[t] != 0);
    if ((threadIdx.x & 63) == 0) {
      const int wbase = t >> 5;
      smaskbits[wbase]     = (unsigned)bal;
      smaskbits[wbase + 1] = (unsigned)(bal >> 32);
    }
  }
  __syncthreads();

  float* orow = out + ((size_t)b * A_DIM + i) * A_DIM;

  if (mi == 0) {  // whole row masked -> zeros, wave exits early
    const f4 z = {0.f, 0.f, 0.f, 0.f};
    #pragma unroll
    for (int c = 0; c < 8; ++c)
      __builtin_nontemporal_store(z, reinterpret_cast<f4*>(orow + (c * 64 + lane) * 4));
    return;
  }

  const float pix  = sx[i];
  const f2    piyz = syz[i];

#define ELEM(nt_, e_, dst_) { \
    const bool on_ = ((((wbits >> (bit + e_)) & 1u) != 0u) & (i != j0 + e_)); \
    const int t_ = on_ ? ((nt_) & (A_DIM - 1)) : 0; \
    const float xx_ = sx[t_]; \
    const f2 yz_ = syz[t_]; \
    const float dx_ = xx_ - pix; \
    const float dy_ = yz_.x - piyz.x; \
    const float dz_ = yz_.y - piyz.y; \
    const float d2_ = dx_ * dx_ + dy_ * dy_ + dz_ * dz_; \
    const float inv_ = fminf(__builtin_amdgcn_rsqf(d2_), 1e8f); \
    dst_ = on_ ? inv_ : 0.0f; }

#define PROC8(c, nA, nB) { \
    const int j0 = ((c) * 64 + lane) * 8; \
    const unsigned wbits = smaskbits[(c) * 16 + (lane >> 2)]; \
    const int bit = (lane & 3) * 8; \
    f4 r0, r1; \
    ELEM(nA.x, 0, r0.x); \
    ELEM(nA.y, 1, r0.y); \
    ELEM(nA.z, 2, r0.z); \
    ELEM(nA.w, 3, r0.w); \
    ELEM(nB.x, 4, r1.x); \
    ELEM(nB.y, 5, r1.y); \
    ELEM(nB.z, 6, r1.z); \
    ELEM(nB.w, 7, r1.w); \
    __builtin_nontemporal_store(r0, reinterpret_cast<f4*>(orow + j0)); \
    __builtin_nontemporal_store(r1, reinterpret_cast<f4*>(orow + j0 + 4)); }

  // 4 chunks, 4 int4 always in flight
  PROC8(0, nA0, nB0); nA0 = LDN(2, 0); nB0 = LDN(2, 1);
  PROC8(1, nA1, nB1); nA1 = LDN(3, 0); nB1 = LDN(3, 1);
  PROC8(2, nA0, nB0);
  PROC8(3, nA1, nB1);

#undef PROC8
#undef ELEM
#undef LDN
}

extern "C" void kernel_launch(void* const* d_in, const int* in_sizes, int n_in,
                              void* d_out, int out_size, void* d_ws, size_t ws_size,
                              hipStream_t stream) {
  const float* pos  = (const float*)d_in[0];  // [4,2048,3] f32
  const int*   nbr  = (const int*)d_in[1];    // [4,2048,2048] int32
  const int*   mask = (const int*)d_in[2];    // [4,2048] int32 (bool)
  float*       out  = (float*)d_out;          // [4,2048,2048] f32

  const int B = in_sizes[2] / A_DIM;          // 4
  const int grid = B * (A_DIM / WPB);         // 1024 blocks

  atom_distances_kernel<<<grid, NTHR, 0, stream>>>(pos, nbr, mask, out);
}

// Round 8
// 21.746 us; speedup vs baseline: 1.3084x; 1.3084x over previous
//
#include <hip/hip_runtime.h>

// AtomDistances: out[b,i,j] = mask[b,i]&&mask[b,j]&&(i!=j)
//                  ? 1/(safe_norm(pos[b,nbr[b,i,j]] - pos[b,i]) + 1e-8) : 0
// B=4, A=2048.
//
// R8 = R6 + 2 rows/wave (ILP-for-TLP trade): 512 blocks x 8 waves, each wave
// owns rows i0+w and i0+8+w. Both-active: dual interleaved chunk pipelines
// (wbits/j0 shared per chunk). One-active: R6 depth-4 pipeline + inactive
// row's zero-stores interleaved. Both-inactive: stream zeros, exit.
// Lane layout stays contiguous-16B (R7 lesson: 32B-stride lanes broke
// coalescing, -6us). No atomics (R5), no prepass (R4).

typedef float f4 __attribute__((ext_vector_type(4)));
typedef float f2 __attribute__((ext_vector_type(2)));

constexpr int A_DIM = 2048;
constexpr int WPB   = 8;            // waves per block
constexpr int RPB   = 16;           // rows per block (2 per wave)
constexpr int NTHR  = WPB * 64;     // 512

__global__ __launch_bounds__(NTHR, 8) void atom_distances_kernel(
    const float* __restrict__ pos,    // [B, A, 3]
    const int*   __restrict__ nbr,    // [B, A, A]
    const int*   __restrict__ mask,   // [B, A]
    float*       __restrict__ out) {  // [B, A, A]
  __shared__ float    sx[A_DIM];             // 8 KB
  __shared__ f2       syz[A_DIM];            // 16 KB
  __shared__ unsigned smaskbits[A_DIM / 32]; // 256 B

  const int blocks_per_b = A_DIM / RPB;      // 128
  const int b  = blockIdx.x / blocks_per_b;
  const int i0 = (blockIdx.x % blocks_per_b) * RPB;

  const float* posb  = pos  + (size_t)b * A_DIM * 3;
  const int*   maskb = mask + (size_t)b * A_DIM;

  const int w    = threadIdx.x >> 6;
  const int lane = threadIdx.x & 63;
  const int iA   = i0 + w;
  const int iB   = i0 + WPB + w;

  const int miA = maskb[iA];                 // wave-uniform broadcast loads
  const int miB = maskb[iB];
  const int* nrowA = nbr + ((size_t)b * A_DIM + iA) * A_DIM;
  const int* nrowB = nbr + ((size_t)b * A_DIM + iB) * A_DIM;

#define LDA(c) (*reinterpret_cast<const int4*>(nrowA + ((c) * 64 + lane) * 4))
#define LDB(c) (*reinterpret_cast<const int4*>(nrowB + ((c) * 64 + lane) * 4))

  // prefetch 2 chunks per active row BEFORE the barrier (hides under staging)
  int4 a0, a1, b0, b1;
  if (miA) { a0 = LDA(0); a1 = LDA(1); }
  if (miB) { b0 = LDB(0); b1 = LDB(1); }

  for (int t = threadIdx.x; t < A_DIM; t += NTHR) {
    sx[t] = posb[3 * t + 0];
    f2 yz; yz.x = posb[3 * t + 1]; yz.y = posb[3 * t + 2];
    syz[t] = yz;
  }
  for (int r = 0; r < A_DIM / NTHR; ++r) {   // 4 rounds
    const int t = r * NTHR + threadIdx.x;
    const unsigned long long bal = __ballot(maskb[t] != 0);
    if ((threadIdx.x & 63) == 0) {
      const int wbase = t >> 5;
      smaskbits[wbase]     = (unsigned)bal;
      smaskbits[wbase + 1] = (unsigned)(bal >> 32);
    }
  }
  __syncthreads();

  float* orowA = out + ((size_t)b * A_DIM + iA) * A_DIM;
  float* orowB = out + ((size_t)b * A_DIM + iB) * A_DIM;
  const f4 zf4 = {0.f, 0.f, 0.f, 0.f};

#define ZST(o_, c_) __builtin_nontemporal_store(zf4, \
    reinterpret_cast<f4*>((o_) + ((c_) * 64 + lane) * 4))

  if (!miA && !miB) {  // both rows masked: stream zeros, exit
    #pragma unroll
    for (int c = 0; c < 8; ++c) { ZST(orowA, c); ZST(orowB, c); }
    return;
  }

#define ELEM(nt_, e_, dst_, i_, pix_, piyz_) { \
    const bool on_ = ((((wbits >> (bit + e_)) & 1u) != 0u) & ((i_) != j0 + e_)); \
    const int t_ = on_ ? ((nt_) & (A_DIM - 1)) : 0; \
    const float xx_ = sx[t_]; \
    const f2 yz_ = syz[t_]; \
    const float dx_ = xx_ - pix_; \
    const float dy_ = yz_.x - piyz_.x; \
    const float dz_ = yz_.y - piyz_.y; \
    const float d2_ = dx_ * dx_ + dy_ * dy_ + dz_ * dz_; \
    const float inv_ = fminf(__builtin_amdgcn_rsqf(d2_), 1e8f); \
    dst_ = on_ ? inv_ : 0.0f; }

#define CHUNKHDR(c) \
    const int j0 = ((c) * 64 + lane) * 4; \
    const unsigned wbits = smaskbits[(c) * 8 + (lane >> 3)]; \
    const int bit = (lane & 7) * 4;

#define PROC4(n_, i_, pix_, piyz_, orow_) { \
    f4 r_; \
    ELEM(n_.x, 0, r_.x, i_, pix_, piyz_); \
    ELEM(n_.y, 1, r_.y, i_, pix_, piyz_); \
    ELEM(n_.z, 2, r_.z, i_, pix_, piyz_); \
    ELEM(n_.w, 3, r_.w, i_, pix_, piyz_); \
    __builtin_nontemporal_store(r_, reinterpret_cast<f4*>((orow_) + j0)); }

  if (miA && miB) {  // dual interleaved pipelines, 4 int4 in flight
    const float pixA = sx[iA]; const f2 piyzA = syz[iA];
    const float pixB = sx[iB]; const f2 piyzB = syz[iB];
    { CHUNKHDR(0); PROC4(a0, iA, pixA, piyzA, orowA); PROC4(b0, iB, pixB, piyzB, orowB); }
    a0 = LDA(2); b0 = LDB(2);
    { CHUNKHDR(1); PROC4(a1, iA, pixA, piyzA, orowA); PROC4(b1, iB, pixB, piyzB, orowB); }
    a1 = LDA(3); b1 = LDB(3);
    { CHUNKHDR(2); PROC4(a0, iA, pixA, piyzA, orowA); PROC4(b0, iB, pixB, piyzB, orowB); }
    a0 = LDA(4); b0 = LDB(4);
    { CHUNKHDR(3); PROC4(a1, iA, pixA, piyzA, orowA); PROC4(b1, iB, pixB, piyzB, orowB); }
    a1 = LDA(5); b1 = LDB(5);
    { CHUNKHDR(4); PROC4(a0, iA, pixA, piyzA, orowA); PROC4(b0, iB, pixB, piyzB, orowB); }
    a0 = LDA(6); b0 = LDB(6);
    { CHUNKHDR(5); PROC4(a1, iA, pixA, piyzA, orowA); PROC4(b1, iB, pixB, piyzB, orowB); }
    a1 = LDA(7); b1 = LDB(7);
    { CHUNKHDR(6); PROC4(a0, iA, pixA, piyzA, orowA); PROC4(b0, iB, pixB, piyzB, orowB); }
    { CHUNKHDR(7); PROC4(a1, iA, pixA, piyzA, orowA); PROC4(b1, iB, pixB, piyzB, orowB); }
    return;
  }

  // exactly one active row: normalize (wave-uniform selects), R6 depth-4
  const int    i1    = miA ? iA : iB;
  const int*   nrow1 = miA ? nrowA : nrowB;
  float*       orow1 = miA ? orowA : orowB;
  float*       orow0 = miA ? orowB : orowA;  // inactive: zeros
  int4 n0 = miA ? a0 : b0;
  int4 n1 = miA ? a1 : b1;
  const float pix  = sx[i1];
  const f2    piyz = syz[i1];

#define LD1(c) (*reinterpret_cast<const int4*>(nrow1 + ((c) * 64 + lane) * 4))

  int4 n2 = LD1(2), n3 = LD1(3);
  { CHUNKHDR(0); PROC4(n0, i1, pix, piyz, orow1); ZST(orow0, 0); } n0 = LD1(4);
  { CHUNKHDR(1); PROC4(n1, i1, pix, piyz, orow1); ZST(orow0, 1); } n1 = LD1(5);
  { CHUNKHDR(2); PROC4(n2, i1, pix, piyz, orow1); ZST(orow0, 2); } n2 = LD1(6);
  { CHUNKHDR(3); PROC4(n3, i1, pix, piyz, orow1); ZST(orow0, 3); } n3 = LD1(7);
  { CHUNKHDR(4); PROC4(n0, i1, pix, piyz, orow1); ZST(orow0, 4); }
  { CHUNKHDR(5); PROC4(n1, i1, pix, piyz, orow1); ZST(orow0, 5); }
  { CHUNKHDR(6); PROC4(n2, i1, pix, piyz, orow1); ZST(orow0, 6); }
  { CHUNKHDR(7); PROC4(n3, i1, pix, piyz, orow1); ZST(orow0, 7); }

#undef LD1
#undef PROC4
#undef CHUNKHDR
#undef ELEM
#undef ZST
#undef LDA
#undef LDB
}

extern "C" void kernel_launch(void* const* d_in, const int* in_sizes, int n_in,
                              void* d_out, int out_size, void* d_ws, size_t ws_size,
                              hipStream_t stream) {
  const float* pos  = (const float*)d_in[0];  // [4,2048,3] f32
  const int*   nbr  = (const int*)d_in[1];    // [4,2048,2048] int32
  const int*   mask = (const int*)d_in[2];    // [4,2048] int32 (bool)
  float*       out  = (float*)d_out;          // [4,2048,2048] f32

  const int B = in_sizes[2] / A_DIM;          // 4
  const int grid = B * (A_DIM / RPB);         // 512 blocks

  atom_distances_kernel<<<grid, NTHR, 0, stream>>>(pos, nbr, mask, out);
}